// Round 2
// baseline (122.117 us; speedup 1.0000x reference)
//
#include <hip/hip_runtime.h>

#define T_LEN 512
#define I_LEN 5

// DPP cross-lane read: lane l receives src from lane (CTRL pattern).
// All involutions within 16-lane rows:
//   0xB1  quad_perm [1,0,3,2]  -> lane ^ 1
//   0x4E  quad_perm [2,3,0,1]  -> lane ^ 2
//   0x141 row_half_mirror      -> lane ^ 7
//   0x140 row_mirror           -> lane ^ 15
template<int CTRL>
__device__ __forceinline__ float fdpp(float x) {
    return __int_as_float(__builtin_amdgcn_update_dpp(
        0, __float_as_int(x), CTRL, 0xF, 0xF, true));
}

__device__ __forceinline__ float tanh_fast(float x) {
    // tanh(x) = 1 - 2/(exp(2x)+1); exp(2x) = exp2(x * 2*log2(e))
    float e = __builtin_exp2f(x * 2.8853900817779268f);
    float r = __builtin_amdgcn_rcpf(e + 1.0f);
    return __builtin_fmaf(-2.0f, r, 1.0f); // saturates to +/-1 correctly
}

// Component extract with compile-time-constant idx (folds after unroll).
__device__ __forceinline__ float f4_at(const float4* b, int idx) {
    const float4 v = b[idx >> 2];
    switch (idx & 3) {
        case 0: return v.x;
        case 1: return v.y;
        case 2: return v.z;
        default: return v.w;
    }
}

// 8 timesteps from a 10-float4 (40-float) register block.
__device__ __forceinline__ void steps8(const float4* __restrict__ q, float& h,
                                       const float* __restrict__ wih,
                                       const float* __restrict__ whh,
                                       float bias) {
#pragma unroll
    for (int s = 0; s < 8; ++s) {
        const float x0 = f4_at(q, 5 * s + 0);
        const float x1 = f4_at(q, 5 * s + 1);
        const float x2 = f4_at(q, 5 * s + 2);
        const float x3 = f4_at(q, 5 * s + 3);
        const float x4 = f4_at(q, 5 * s + 4);

        // input projection, 3 parallel chains
        float acc0 = __builtin_fmaf(x0, wih[0], bias);
        float acc1 = x1 * wih[1];
        acc1 = __builtin_fmaf(x2, wih[2], acc1);
        float acc2 = x3 * wih[3];
        acc2 = __builtin_fmaf(x4, wih[4], acc2);

        // DPP allgather: hr[m] = h_{j^m}
        float hr[16];
        hr[0]  = h;
        hr[1]  = fdpp<0xB1>(hr[0]);
        hr[2]  = fdpp<0x4E>(hr[0]);
        hr[3]  = fdpp<0x4E>(hr[1]);
        hr[7]  = fdpp<0x141>(hr[0]);
        hr[6]  = fdpp<0x141>(hr[1]);
        hr[5]  = fdpp<0x141>(hr[2]);
        hr[4]  = fdpp<0x141>(hr[3]);
        hr[15] = fdpp<0x140>(hr[0]);
        hr[14] = fdpp<0x140>(hr[1]);
        hr[13] = fdpp<0x140>(hr[2]);
        hr[12] = fdpp<0x140>(hr[3]);
        hr[11] = fdpp<0x140>(hr[4]);
        hr[10] = fdpp<0x140>(hr[5]);
        hr[9]  = fdpp<0x140>(hr[6]);
        hr[8]  = fdpp<0x140>(hr[7]);

        // recurrent matvec: 4 parallel accumulator chains
        float a0 = acc0, a1 = acc1, a2 = acc2, a3 = 0.0f;
#pragma unroll
        for (int m = 0; m < 16; m += 4) {
            a0 = __builtin_fmaf(hr[m + 0], whh[m + 0], a0);
            a1 = __builtin_fmaf(hr[m + 1], whh[m + 1], a1);
            a2 = __builtin_fmaf(hr[m + 2], whh[m + 2], a2);
            a3 = __builtin_fmaf(hr[m + 3], whh[m + 3], a3);
        }
        h = tanh_fast((a0 + a1) + (a2 + a3));
    }
}

__global__ __launch_bounds__(256, 2) void rnn_m2o_kernel(
    const float* __restrict__ x, const float* __restrict__ W_ih,
    const float* __restrict__ W_hh, const float* __restrict__ b_ih,
    const float* __restrict__ b_hh, const float* __restrict__ W_fc,
    const float* __restrict__ b_fc, float* __restrict__ out)
{
    const int j   = threadIdx.x & 15;       // hidden unit owned by this lane
    const int grp = threadIdx.x >> 4;       // group-of-16 within block
    const int b   = blockIdx.x * 16 + grp;  // batch element

    float wih[I_LEN];
#pragma unroll
    for (int i = 0; i < I_LEN; ++i) wih[i] = W_ih[j * I_LEN + i];
    const float bias = b_ih[j] + b_hh[j];

    // XOR-skewed W_hh row: whh[m] = W_hh[j][j^m], pairs with h from lane j^m
    float whh[16];
#pragma unroll
    for (int m = 0; m < 16; ++m) whh[m] = W_hh[j * 16 + (j ^ m)];

    const float wfc = W_fc[j];
    const float bfc = b_fc[0];

    const float* xb = x + (size_t)b * (T_LEN * I_LEN);
    const float4* px = reinterpret_cast<const float4*>(xb);

    // Double-buffered 8-step blocks: 8 steps * 5 floats = 40 floats = 10 f4.
    // (t' ≡ 0 mod 8 → t'*5 ≡ 0 mod 4, always float4-aligned.)
    float4 A[10], B[10];
#pragma unroll
    for (int i = 0; i < 10; ++i) A[i] = px[i];   // steps 0..7

    float h = 0.0f;

    for (int t = 0; t < T_LEN; t += 16) {
        // prefetch steps t+8..t+15 (t <= 496 -> t+8 <= 504, always valid)
        const float4* pB = px + ((t + 8) * I_LEN) / 4;
#pragma unroll
        for (int i = 0; i < 10; ++i) B[i] = pB[i];

        steps8(A, h, wih, whh, bias);   // ~8 steps of compute hide B's latency

        // prefetch steps t+16..t+23 for next iteration (dummy reload at end)
        const int tn = (t + 16 < T_LEN) ? (t + 16) : 0;
        const float4* pA = px + (tn * I_LEN) / 4;
#pragma unroll
        for (int i = 0; i < 10; ++i) A[i] = pA[i];

        steps8(B, h, wih, whh, bias);   // hides A's latency
    }

    // fc + sigmoid: reduce h_j * wfc_j over the 16-lane group via DPP
    float r = h * wfc;
    r += fdpp<0xB1>(r);
    r += fdpp<0x4E>(r);
    r += fdpp<0x141>(r);
    r += fdpp<0x140>(r);
    if (j == 0) {
        float z = r + bfc;
        float sg = __builtin_amdgcn_rcpf(
            1.0f + __builtin_exp2f(z * -1.4426950408889634f));
        out[b] = sg;
    }
}

extern "C" void kernel_launch(void* const* d_in, const int* in_sizes, int n_in,
                              void* d_out, int out_size, void* d_ws, size_t ws_size,
                              hipStream_t stream) {
    const float* x    = (const float*)d_in[0];
    const float* W_ih = (const float*)d_in[1];
    const float* W_hh = (const float*)d_in[2];
    const float* b_ih = (const float*)d_in[3];
    const float* b_hh = (const float*)d_in[4];
    const float* W_fc = (const float*)d_in[5];
    const float* b_fc = (const float*)d_in[6];
    float* out = (float*)d_out;

    const int B = in_sizes[0] / (T_LEN * I_LEN);   // 8192
    const int blocks = B / 16;                     // 16 batch elements / block
    rnn_m2o_kernel<<<blocks, 256, 0, stream>>>(x, W_ih, W_hh, b_ih, b_hh,
                                               W_fc, b_fc, out);
}

// Round 3
// 103.793 us; speedup vs baseline: 1.1765x; 1.1765x over previous
//
#include <hip/hip_runtime.h>
#include <stdint.h>

#define T_LEN 512
#define I_LEN 5
#define CHUNK 8                    // timesteps per staged chunk
#define NCHUNK (T_LEN / CHUNK)     // 64
#define LOOKAHEAD 3                // chunks in flight (4 LDS slots)

// DPP cross-lane read: lane l receives src from lane (CTRL pattern).
// All involutions within 16-lane rows:
//   0xB1  quad_perm [1,0,3,2]  -> lane ^ 1
//   0x4E  quad_perm [2,3,0,1]  -> lane ^ 2
//   0x141 row_half_mirror      -> lane ^ 7
//   0x140 row_mirror           -> lane ^ 15
template<int CTRL>
__device__ __forceinline__ float fdpp(float x) {
    return __int_as_float(__builtin_amdgcn_update_dpp(
        0, __float_as_int(x), CTRL, 0xF, 0xF, true));
}

__device__ __forceinline__ float tanh_fast(float x) {
    // tanh(x) = 1 - 2/(exp(2x)+1); exp(2x) = exp2(x * 2*log2(e))
    float e = __builtin_exp2f(x * 2.8853900817779268f);
    float r = __builtin_amdgcn_rcpf(e + 1.0f);
    return __builtin_fmaf(-2.0f, r, 1.0f); // saturates to +/-1 correctly
}

// One global_load_lds_dwordx4: lane l loads 16B from its own global addr,
// writes LDS at (wave-uniform base) + l*16. CK-style addrspace casts.
__device__ __forceinline__ void gload_lds16(const float* g, float* l) {
    auto gp = reinterpret_cast<const __attribute__((address_space(1))) float*>(
        reinterpret_cast<uintptr_t>(g));
    auto lp = reinterpret_cast<__attribute__((address_space(3))) float*>(
        reinterpret_cast<uintptr_t>(l));
    __builtin_amdgcn_global_load_lds(gp, lp, 16, 0, 0);
}

// Component extract with compile-time-constant idx (folds after unroll).
__device__ __forceinline__ float f4_at(const float4* b, int idx) {
    const float4 v = b[idx >> 2];
    switch (idx & 3) {
        case 0: return v.x;
        case 1: return v.y;
        case 2: return v.z;
        default: return v.w;
    }
}

// 8 timesteps from a 10-float4 (40-float) register block.
__device__ __forceinline__ void steps8(const float4* __restrict__ q, float& h,
                                       const float* __restrict__ wih,
                                       const float* __restrict__ whh,
                                       float bias) {
#pragma unroll
    for (int s = 0; s < 8; ++s) {
        const float x0 = f4_at(q, 5 * s + 0);
        const float x1 = f4_at(q, 5 * s + 1);
        const float x2 = f4_at(q, 5 * s + 2);
        const float x3 = f4_at(q, 5 * s + 3);
        const float x4 = f4_at(q, 5 * s + 4);

        // input projection, 3 parallel chains
        float acc0 = __builtin_fmaf(x0, wih[0], bias);
        float acc1 = x1 * wih[1];
        acc1 = __builtin_fmaf(x2, wih[2], acc1);
        float acc2 = x3 * wih[3];
        acc2 = __builtin_fmaf(x4, wih[4], acc2);

        // DPP allgather: hr[m] = h_{j^m}
        float hr[16];
        hr[0]  = h;
        hr[1]  = fdpp<0xB1>(hr[0]);
        hr[2]  = fdpp<0x4E>(hr[0]);
        hr[3]  = fdpp<0x4E>(hr[1]);
        hr[7]  = fdpp<0x141>(hr[0]);
        hr[6]  = fdpp<0x141>(hr[1]);
        hr[5]  = fdpp<0x141>(hr[2]);
        hr[4]  = fdpp<0x141>(hr[3]);
        hr[15] = fdpp<0x140>(hr[0]);
        hr[14] = fdpp<0x140>(hr[1]);
        hr[13] = fdpp<0x140>(hr[2]);
        hr[12] = fdpp<0x140>(hr[3]);
        hr[11] = fdpp<0x140>(hr[4]);
        hr[10] = fdpp<0x140>(hr[5]);
        hr[9]  = fdpp<0x140>(hr[6]);
        hr[8]  = fdpp<0x140>(hr[7]);

        // recurrent matvec: 4 parallel accumulator chains
        float a0 = acc0, a1 = acc1, a2 = acc2, a3 = 0.0f;
#pragma unroll
        for (int m = 0; m < 16; m += 4) {
            a0 = __builtin_fmaf(hr[m + 0], whh[m + 0], a0);
            a1 = __builtin_fmaf(hr[m + 1], whh[m + 1], a1);
            a2 = __builtin_fmaf(hr[m + 2], whh[m + 2], a2);
            a3 = __builtin_fmaf(hr[m + 3], whh[m + 3], a3);
        }
        h = tanh_fast((a0 + a1) + (a2 + a3));
    }
}

__global__ __launch_bounds__(256, 2) void rnn_m2o_kernel(
    const float* __restrict__ x, const float* __restrict__ W_ih,
    const float* __restrict__ W_hh, const float* __restrict__ b_ih,
    const float* __restrict__ b_hh, const float* __restrict__ W_fc,
    const float* __restrict__ b_fc, float* __restrict__ out)
{
    const int tid  = threadIdx.x;
    const int wave = tid >> 6;        // 0..3
    const int lane = tid & 63;
    const int grp  = (tid >> 4) & 3;  // group-of-16 within wave
    const int j    = tid & 15;        // hidden unit owned by this lane
    const int b    = blockIdx.x * 16 + wave * 4 + grp;  // batch element

    // [wave][slot][4 batches x 64-dword padded slots] = 16 KiB
    __shared__ float lds_x[4][4][256];

    float wih[I_LEN];
#pragma unroll
    for (int i = 0; i < I_LEN; ++i) wih[i] = W_ih[j * I_LEN + i];
    const float bias = b_ih[j] + b_hh[j];

    // XOR-skewed W_hh row: whh[m] = W_hh[j][j^m], pairs with h from lane j^m
    float whh[16];
#pragma unroll
    for (int m = 0; m < 16; ++m) whh[m] = W_hh[j * 16 + (j ^ m)];

    const float wfc = W_fc[j];
    const float bfc = b_fc[0];

    // Per-lane staging source: lane l serves batch (l>>4), float4 (l&15).
    // Only float4s 0..9 are real (40 floats/chunk); lanes 10..15 load pad.
    const int lb   = blockIdx.x * 16 + wave * 4 + (lane >> 4);
    const int o16  = lane & 15;
    const int ofl  = (o16 < 10) ? o16 * 4 : 0;   // float offset within chunk
    const float* gsrc = x + (size_t)lb * (T_LEN * I_LEN) + ofl;

    // Prologue: stage chunks 0..2 into slots 0..2.
#pragma unroll
    for (int c = 0; c < LOOKAHEAD; ++c)
        gload_lds16(gsrc + c * (CHUNK * I_LEN), &lds_x[wave][c][0]);

    float h = 0.0f;

    for (int n = 0; n < NCHUNK; ++n) {
        // Issue chunk n+3 into slot (n+3)&3 (wraps to a harmless dummy
        // reload of chunks 0..2 at the tail — those slots are dead by then).
        const int cpf = (n + LOOKAHEAD) & (NCHUNK - 1);
        gload_lds16(gsrc + cpf * (CHUNK * I_LEN),
                    &lds_x[wave][(n + LOOKAHEAD) & 3][0]);

        // Counted wait: 3 newer chunks may stay in flight; chunk n is done.
        asm volatile("s_waitcnt vmcnt(3)" ::: "memory");

        const float4* src =
            reinterpret_cast<const float4*>(&lds_x[wave][n & 3][grp * 64]);
        float4 q[10];
#pragma unroll
        for (int i = 0; i < 10; ++i) q[i] = src[i];

        steps8(q, h, wih, whh, bias);
    }

    // fc + sigmoid: reduce h_j * wfc_j over the 16-lane group via DPP
    float r = h * wfc;
    r += fdpp<0xB1>(r);
    r += fdpp<0x4E>(r);
    r += fdpp<0x141>(r);
    r += fdpp<0x140>(r);
    if (j == 0) {
        float z = r + bfc;
        float sg = __builtin_amdgcn_rcpf(
            1.0f + __builtin_exp2f(z * -1.4426950408889634f));
        out[b] = sg;
    }
}

extern "C" void kernel_launch(void* const* d_in, const int* in_sizes, int n_in,
                              void* d_out, int out_size, void* d_ws, size_t ws_size,
                              hipStream_t stream) {
    const float* x    = (const float*)d_in[0];
    const float* W_ih = (const float*)d_in[1];
    const float* W_hh = (const float*)d_in[2];
    const float* b_ih = (const float*)d_in[3];
    const float* b_hh = (const float*)d_in[4];
    const float* W_fc = (const float*)d_in[5];
    const float* b_fc = (const float*)d_in[6];
    float* out = (float*)d_out;

    const int B = in_sizes[0] / (T_LEN * I_LEN);   // 8192
    const int blocks = B / 16;                     // 16 batch elements / block
    rnn_m2o_kernel<<<blocks, 256, 0, stream>>>(x, W_ih, W_hh, b_ih, b_hh,
                                               W_fc, b_fc, out);
}

// Round 4
// 90.068 us; speedup vs baseline: 1.3558x; 1.1524x over previous
//
#include <hip/hip_runtime.h>
#include <stdint.h>

#define T_LEN 512
#define I_LEN 5
#define CHUNK 8                    // timesteps per staged chunk
#define NCHUNK (T_LEN / CHUNK)     // 64

// DPP cross-lane read: lane l receives src from lane (CTRL pattern).
// All involutions within 16-lane rows:
//   0xB1  quad_perm [1,0,3,2]  -> lane ^ 1
//   0x4E  quad_perm [2,3,0,1]  -> lane ^ 2
//   0x141 row_half_mirror      -> lane ^ 7
//   0x140 row_mirror           -> lane ^ 15
template<int CTRL>
__device__ __forceinline__ float fdpp(float x) {
    return __int_as_float(__builtin_amdgcn_update_dpp(
        0, __float_as_int(x), CTRL, 0xF, 0xF, true));
}

__device__ __forceinline__ float tanh_fast(float x) {
    float e = __builtin_exp2f(x * 2.8853900817779268f);
    float r = __builtin_amdgcn_rcpf(e + 1.0f);
    return __builtin_fmaf(-2.0f, r, 1.0f); // saturates to +/-1 correctly
}

// One global_load_lds_dwordx4: lane l loads 16B from its own global addr,
// writes LDS at (wave-uniform base) + lane*16.
__device__ __forceinline__ void gload_lds16(const float* g, float* l) {
    auto gp = reinterpret_cast<const __attribute__((address_space(1))) float*>(
        reinterpret_cast<uintptr_t>(g));
    auto lp = reinterpret_cast<__attribute__((address_space(3))) float*>(
        reinterpret_cast<uintptr_t>(l));
    __builtin_amdgcn_global_load_lds(gp, lp, 16, 0, 0);
}

// Volatile asm ds_read_b128: cannot be sunk or split by the scheduler.
#define DSR(dst, addr, OFFSTR)                                              \
    asm volatile("ds_read_b128 %0, %1 offset:" OFFSTR                      \
                 : "=v"(dst) : "v"(addr))

// Read 10 float4s for one (group, slot): addresses addr + i*64 bytes.
#define DSR10(q, addr)                                                      \
    do {                                                                    \
        DSR((q)[0], (addr), "0");   DSR((q)[1], (addr), "64");              \
        DSR((q)[2], (addr), "128"); DSR((q)[3], (addr), "192");             \
        DSR((q)[4], (addr), "256"); DSR((q)[5], (addr), "320");             \
        DSR((q)[6], (addr), "384"); DSR((q)[7], (addr), "448");             \
        DSR((q)[8], (addr), "512"); DSR((q)[9], (addr), "576");             \
    } while (0)

#define WAIT_LGKM0()                                                        \
    do {                                                                    \
        asm volatile("s_waitcnt lgkmcnt(0)" ::: "memory");                  \
        __builtin_amdgcn_sched_barrier(0);                                  \
    } while (0)

#define WAIT_VM(N)                                                          \
    asm volatile("s_waitcnt vmcnt(" #N ")" ::: "memory")

// Component extract with compile-time-constant idx (folds after unroll).
__device__ __forceinline__ float f4_at(const float4* b, int idx) {
    const float4 v = b[idx >> 2];
    switch (idx & 3) {
        case 0: return v.x;
        case 1: return v.y;
        case 2: return v.z;
        default: return v.w;
    }
}

// 8 timesteps from a 10-float4 (40-float) register block.
__device__ __forceinline__ void steps8(const float4* __restrict__ q, float& h,
                                       const float* __restrict__ wih,
                                       const float* __restrict__ whh,
                                       float bias) {
#pragma unroll
    for (int s = 0; s < 8; ++s) {
        const float x0 = f4_at(q, 5 * s + 0);
        const float x1 = f4_at(q, 5 * s + 1);
        const float x2 = f4_at(q, 5 * s + 2);
        const float x3 = f4_at(q, 5 * s + 3);
        const float x4 = f4_at(q, 5 * s + 4);

        float acc0 = __builtin_fmaf(x0, wih[0], bias);
        float acc1 = x1 * wih[1];
        acc1 = __builtin_fmaf(x2, wih[2], acc1);
        float acc2 = x3 * wih[3];
        acc2 = __builtin_fmaf(x4, wih[4], acc2);

        // DPP allgather: hr[m] = h_{j^m}
        float hr[16];
        hr[0]  = h;
        hr[1]  = fdpp<0xB1>(hr[0]);
        hr[2]  = fdpp<0x4E>(hr[0]);
        hr[3]  = fdpp<0x4E>(hr[1]);
        hr[7]  = fdpp<0x141>(hr[0]);
        hr[6]  = fdpp<0x141>(hr[1]);
        hr[5]  = fdpp<0x141>(hr[2]);
        hr[4]  = fdpp<0x141>(hr[3]);
        hr[15] = fdpp<0x140>(hr[0]);
        hr[14] = fdpp<0x140>(hr[1]);
        hr[13] = fdpp<0x140>(hr[2]);
        hr[12] = fdpp<0x140>(hr[3]);
        hr[11] = fdpp<0x140>(hr[4]);
        hr[10] = fdpp<0x140>(hr[5]);
        hr[9]  = fdpp<0x140>(hr[6]);
        hr[8]  = fdpp<0x140>(hr[7]);

        float a0 = acc0, a1 = acc1, a2 = acc2, a3 = 0.0f;
#pragma unroll
        for (int m = 0; m < 16; m += 4) {
            a0 = __builtin_fmaf(hr[m + 0], whh[m + 0], a0);
            a1 = __builtin_fmaf(hr[m + 1], whh[m + 1], a1);
            a2 = __builtin_fmaf(hr[m + 2], whh[m + 2], a2);
            a3 = __builtin_fmaf(hr[m + 3], whh[m + 3], a3);
        }
        h = tanh_fast((a0 + a1) + (a2 + a3));
    }
}

__global__ __launch_bounds__(256, 2) void rnn_m2o_kernel(
    const float* __restrict__ x, const float* __restrict__ W_ih,
    const float* __restrict__ W_hh, const float* __restrict__ b_ih,
    const float* __restrict__ b_hh, const float* __restrict__ W_fc,
    const float* __restrict__ b_fc, float* __restrict__ out)
{
    const int tid  = threadIdx.x;
    const int wave = tid >> 6;        // 0..3
    const int lane = tid & 63;
    const int grp  = (tid >> 4) & 3;  // group-of-16 within wave
    const int j    = tid & 15;        // hidden unit owned by this lane
    const int b    = blockIdx.x * 16 + wave * 4 + grp;  // batch element

    // [wave][slot][256 dwords]: slot holds one chunk for 4 batches,
    // interleaved so (f4 i, batch b') sits at dword (4i+b')*4.
    __shared__ float lds_x[4][4][256];

    float wih[I_LEN];
#pragma unroll
    for (int i = 0; i < I_LEN; ++i) wih[i] = W_ih[j * I_LEN + i];
    const float bias = b_ih[j] + b_hh[j];

    // XOR-skewed W_hh row: whh[m] = W_hh[j][j^m], pairs with h from lane j^m
    float whh[16];
#pragma unroll
    for (int m = 0; m < 16; ++m) whh[m] = W_hh[j * 16 + (j ^ m)];

    const float wfc = W_fc[j];
    const float bfc = b_fc[0];

    // Staging source: lane l serves batch (l&3), float4 (l>>2).
    // Linear LDS write (lane*16B) then lands (f4 i, batch b') at dword
    // (4i+b')*4  ->  group g's reads hit banks {4g..4g+3}: conflict-free.
    const int f4i = lane >> 2;
    const int bat = lane & 3;
    const int lb  = blockIdx.x * 16 + wave * 4 + bat;
    const int ofl = (f4i < 10) ? f4i * 4 : 0;   // float offset within chunk
    const float* gsrc = x + (size_t)lb * (T_LEN * I_LEN) + ofl;

    const uint32_t lds_grp =
        (uint32_t)(uintptr_t)&lds_x[wave][0][0] + (uint32_t)(grp * 16);

    float4 qA[10], qB[10];
    float h = 0.0f;

    // Prologue: stage chunks 0..2, read chunk 0 into qA.
    gload_lds16(gsrc + 0 * (CHUNK * I_LEN), &lds_x[wave][0][0]);
    gload_lds16(gsrc + 1 * (CHUNK * I_LEN), &lds_x[wave][1][0]);
    gload_lds16(gsrc + 2 * (CHUNK * I_LEN), &lds_x[wave][2][0]);
    WAIT_VM(2);                       // chunk 0 landed
    DSR10(qA, lds_grp);               // slot 0
    WAIT_LGKM0();

    for (int n = 0; n < NCHUNK; n += 2) {
        // ---- even phase: compute chunk n (qA), prefetch-read chunk n+1 ----
        {
            const int cpf = (n + 3) & (NCHUNK - 1);
            gload_lds16(gsrc + cpf * (CHUNK * I_LEN),
                        &lds_x[wave][(n + 3) & 3][0]);
            WAIT_VM(2);               // chunk n+1 landed
            const uint32_t aB = lds_grp + (uint32_t)(((n + 1) & 3) * 1024);
            DSR10(qB, aB);
            steps8(qA, h, wih, whh, bias);
            WAIT_LGKM0();
        }
        // ---- odd phase: compute chunk n+1 (qB), prefetch-read chunk n+2 ---
        {
            const int cpf = (n + 4) & (NCHUNK - 1);
            gload_lds16(gsrc + cpf * (CHUNK * I_LEN),
                        &lds_x[wave][(n + 4) & 3][0]);
            WAIT_VM(2);               // chunk n+2 landed
            const uint32_t aA = lds_grp + (uint32_t)(((n + 2) & 3) * 1024);
            DSR10(qA, aA);
            steps8(qB, h, wih, whh, bias);
            WAIT_LGKM0();
        }
    }

    // fc + sigmoid: reduce h_j * wfc_j over the 16-lane group via DPP
    float r = h * wfc;
    r += fdpp<0xB1>(r);
    r += fdpp<0x4E>(r);
    r += fdpp<0x141>(r);
    r += fdpp<0x140>(r);
    if (j == 0) {
        float z = r + bfc;
        float sg = __builtin_amdgcn_rcpf(
            1.0f + __builtin_exp2f(z * -1.4426950408889634f));
        out[b] = sg;
    }
}

extern "C" void kernel_launch(void* const* d_in, const int* in_sizes, int n_in,
                              void* d_out, int out_size, void* d_ws, size_t ws_size,
                              hipStream_t stream) {
    const float* x    = (const float*)d_in[0];
    const float* W_ih = (const float*)d_in[1];
    const float* W_hh = (const float*)d_in[2];
    const float* b_ih = (const float*)d_in[3];
    const float* b_hh = (const float*)d_in[4];
    const float* W_fc = (const float*)d_in[5];
    const float* b_fc = (const float*)d_in[6];
    float* out = (float*)d_out;

    const int B = in_sizes[0] / (T_LEN * I_LEN);   // 8192
    const int blocks = B / 16;                     // 16 batch elements / block
    rnn_m2o_kernel<<<blocks, 256, 0, stream>>>(x, W_ih, W_hh, b_ih, b_hh,
                                               W_fc, b_fc, out);
}